// Round 1
// baseline (41129.633 us; speedup 1.0000x reference)
//
#include <hip/hip_runtime.h>
#include <math.h>

#define B_SZ   32
#define T_SZ   1024
#define IN_SZ  512
#define SEN    512
#define HID    1024
#define MOT    512
#define OUT_SZ 512

// ---------------------------------------------------------------------------
// Generic tiled f32 GEMM:  C[scatter(r), c] = sum_k A[r,k] * op(B)[k,c] + bias[c]
//   A: [M][K] row-major with leading dim lda
//   TB=true : Bm is [N][K] row-major (computes A @ B^T)
//   TB=false: Bm is [K][N] row-major (computes A @ B)
//   C address for row r, col c:  (r % P)*S1 + (r / P)*S2 + c
// Tiles: 64x64 output per block, BK=16, 256 threads, 4x4 per thread.
// All dims assumed multiples of tile sizes (true for this problem).
// ---------------------------------------------------------------------------
template<bool TB>
__global__ __launch_bounds__(256) void gemm_tiled(
    const float* __restrict__ A, const float* __restrict__ Bm,
    const float* __restrict__ bias, float* __restrict__ C,
    int M, int N, int K, int lda,
    int P, long long S1, long long S2)
{
  __shared__ float As[16][64 + 1];
  __shared__ float Bs[16][64 + 1];
  const int tid = threadIdx.x;
  const int n0 = blockIdx.x * 64;
  const int r0 = blockIdx.y * 64;
  const int ty = tid / 16;   // row group 0..15
  const int tx = tid % 16;   // col group 0..15

  float acc[4][4] = {};

  for (int k0 = 0; k0 < K; k0 += 16) {
    // load A tile: As[kk][m]
    {
      const int kk = tid % 16, m0 = tid / 16;
      #pragma unroll
      for (int i = 0; i < 4; i++) {
        const int m = m0 + i * 16;
        As[kk][m] = A[(long long)(r0 + m) * lda + k0 + kk];
      }
    }
    // load B tile: Bs[kk][n]
    if (TB) {
      const int kk = tid % 16, nl0 = tid / 16;
      #pragma unroll
      for (int i = 0; i < 4; i++) {
        const int n = nl0 + i * 16;
        Bs[kk][n] = Bm[(long long)(n0 + n) * K + k0 + kk];
      }
    } else {
      const int nl = tid % 64, kk0 = tid / 64;
      #pragma unroll
      for (int i = 0; i < 4; i++) {
        const int kk = kk0 + i * 4;
        Bs[kk][nl] = Bm[(long long)(k0 + kk) * N + n0 + nl];
      }
    }
    __syncthreads();

    #pragma unroll
    for (int kk = 0; kk < 16; kk++) {
      float av[4], bv[4];
      #pragma unroll
      for (int i = 0; i < 4; i++) av[i] = As[kk][ty * 4 + i];
      #pragma unroll
      for (int j = 0; j < 4; j++) bv[j] = Bs[kk][tx * 4 + j];
      #pragma unroll
      for (int i = 0; i < 4; i++)
        #pragma unroll
        for (int j = 0; j < 4; j++)
          acc[i][j] += av[i] * bv[j];
    }
    __syncthreads();
  }

  #pragma unroll
  for (int i = 0; i < 4; i++) {
    const int r = r0 + ty * 4 + i;
    const long long base = (long long)(r % P) * S1 + (long long)(r / P) * S2;
    #pragma unroll
    for (int j = 0; j < 4; j++) {
      const int c = n0 + tx * 4 + j;
      float v = acc[i][j];
      if (bias) v += bias[c];
      C[base + c] = v;
    }
  }
}

// bias_eff[h] = b_cell[h] + dot(W_x[h,:], b_in)
__global__ void bias_eff_kernel(const float* __restrict__ Wx,
                                const float* __restrict__ b_in,
                                const float* __restrict__ b_cell,
                                float* __restrict__ bias_eff)
{
  const int h = blockIdx.x * 256 + threadIdx.x;
  float s = b_cell[h];
  for (int k = 0; k < SEN; k++) s += Wx[h * SEN + k] * b_in[k];
  bias_eff[h] = s;
}

// One scan step: for every (b, j):
//   z  = pre[t][b][j] + dot(h_in[b,:], W_h[j,:])
//   f  = sigmoid(z)
//   hn = (h_in[b][j] + ts*f*A[j]) / (1 + ts*(1/tau[j] + f))
// grid: HID/8 blocks of 256 threads; thread = (b = tid>>3, jl = tid&7)
__global__ __launch_bounds__(256) void step_kernel(
    const float* __restrict__ h_in, float* __restrict__ h_out,
    const float* __restrict__ Wh, const float* __restrict__ pre_t,
    const float* __restrict__ timespans, int t,
    const float* __restrict__ Avec, const float* __restrict__ tau,
    float* __restrict__ hseq_t)
{
  const int tid = threadIdx.x;
  const int jl = tid & 7;
  const int b  = tid >> 3;
  const int j  = blockIdx.x * 8 + jl;

  const float4* hp = reinterpret_cast<const float4*>(h_in + b * HID);
  const float4* wp = reinterpret_cast<const float4*>(Wh + (long long)j * HID);

  float acc = 0.f;
  #pragma unroll 8
  for (int k = 0; k < HID / 4; k++) {
    const float4 hv = hp[k];
    const float4 wv = wp[k];
    acc += hv.x * wv.x + hv.y * wv.y + hv.z * wv.z + hv.w * wv.w;
  }

  const float z  = acc + pre_t[b * HID + j];
  const float f  = 1.f / (1.f + expf(-z));
  const float ts = timespans[b * T_SZ + t];
  const float h0 = h_in[b * HID + j];
  const float a  = Avec[j];
  const float it = 1.f / tau[j];
  const float hn = (h0 + ts * f * a) / (1.f + ts * (it + f));

  h_out[b * HID + j] = hn;
  if (j < MOT) hseq_t[b * MOT + j] = hn;
}

extern "C" void kernel_launch(void* const* d_in, const int* in_sizes, int n_in,
                              void* d_out, int out_size, void* d_ws, size_t ws_size,
                              hipStream_t stream)
{
  const float* inputs    = (const float*)d_in[0];
  const float* timespans = (const float*)d_in[1];
  const float* init_h    = (const float*)d_in[2];
  const float* W_in      = (const float*)d_in[3];
  const float* b_in      = (const float*)d_in[4];
  const float* W_x       = (const float*)d_in[5];
  const float* W_h       = (const float*)d_in[6];
  const float* b_cell    = (const float*)d_in[7];
  const float* tau       = (const float*)d_in[8];
  const float* A         = (const float*)d_in[9];
  const float* W_out     = (const float*)d_in[10];
  const float* b_out     = (const float*)d_in[11];
  float* out = (float*)d_out;

  float* ws    = (float*)d_ws;
  float* pre   = ws;                                  // T*B*HID   = 33,554,432 f
  float* hseq  = pre   + (size_t)T_SZ * B_SZ * HID;   // T*B*MOT   = 16,777,216 f
  float* Wxi   = hseq  + (size_t)T_SZ * B_SZ * MOT;   // HID*IN_SZ =    524,288 f
  float* beff  = Wxi   + (size_t)HID * IN_SZ;         // HID
  float* hbuf0 = beff  + HID;                         // B*HID
  float* hbuf1 = hbuf0 + (size_t)B_SZ * HID;          // B*HID

  // K0: Wxi = W_x @ W_in   (M=HID, N=IN_SZ, K=SEN), plain C row-major
  gemm_tiled<false><<<dim3(IN_SZ / 64, HID / 64), 256, 0, stream>>>(
      W_x, W_in, nullptr, Wxi, HID, IN_SZ, SEN, SEN,
      1 << 30, (long long)IN_SZ, 0LL);

  bias_eff_kernel<<<HID / 256, 256, 0, stream>>>(W_x, b_in, b_cell, beff);

  // K1: pre[t][b][h] = inputs[r=b*T+t,:] @ Wxi^T + beff
  //     scatter: r -> (b=r/T, t=r%T): addr = (r%1024)*32768 + (r/1024)*1024 + c
  gemm_tiled<true><<<dim3(HID / 64, (B_SZ * T_SZ) / 64), 256, 0, stream>>>(
      inputs, Wxi, beff, pre, B_SZ * T_SZ, HID, IN_SZ, IN_SZ,
      T_SZ, (long long)B_SZ * HID, (long long)HID);

  // scan: 1024 sequential steps, double-buffered h
  for (int t = 0; t < T_SZ; t++) {
    const float* hi = (t == 0) ? init_h : ((t & 1) ? hbuf0 : hbuf1);
    float* ho = (t & 1) ? hbuf1 : hbuf0;
    step_kernel<<<HID / 8, 256, 0, stream>>>(
        hi, ho, W_h, pre + (size_t)t * B_SZ * HID,
        timespans, t, A, tau, hseq + (size_t)t * B_SZ * MOT);
  }

  // K3: out[b][t][o] = hseq[r=t*B+b, :MOT] @ W_out^T + b_out
  //     scatter: r -> (t=r/32, b=r%32): addr = (r%32)*(T*OUT) + (r/32)*OUT + c
  gemm_tiled<true><<<dim3(OUT_SZ / 64, (B_SZ * T_SZ) / 64), 256, 0, stream>>>(
      hseq, W_out, b_out, out, B_SZ * T_SZ, OUT_SZ, MOT, MOT,
      B_SZ, (long long)T_SZ * OUT_SZ, (long long)OUT_SZ);

  // last_state = h after step 1023 (odd -> hbuf1)
  hipMemcpyAsync(out + (size_t)B_SZ * T_SZ * OUT_SZ, hbuf1,
                 (size_t)B_SZ * HID * sizeof(float),
                 hipMemcpyDeviceToDevice, stream);
}